// Round 2
// baseline (424.451 us; speedup 1.0000x reference)
//
#include <hip/hip_runtime.h>
#include <math.h>
#include <stdint.h>

// MFMA fragment types (guide §3, compile-verified on gfx950)
typedef __attribute__((ext_vector_type(8))) short bf16x8;   // 8 bf16 in 4 VGPRs
typedef __attribute__((ext_vector_type(4))) float f32x4;    // 4 fp32 acc

__device__ __forceinline__ unsigned short f2bf(float f) {
    union { float f; unsigned u; } v; v.f = f;
    return (unsigned short)((v.u + 0x7fffu + ((v.u >> 16) & 1u)) >> 16); // RNE
}

// async global->LDS, 16B per lane; LDS dest = firstlane base + lane*16 (m97)
__device__ __forceinline__ void gld_lds16(const void* g, void* l) {
    __builtin_amdgcn_global_load_lds(
        (const __attribute__((address_space(1))) unsigned*)(uintptr_t)g,
        (__attribute__((address_space(3))) unsigned*)(uintptr_t)l, 16, 0, 0);
}

// ---------------- fp32 -> bf16 elementwise (x4 vectorized) ----------------
__global__ void k_convert(const float* __restrict__ in, unsigned short* __restrict__ out, int n4) {
    int i = blockIdx.x * blockDim.x + threadIdx.x;
    if (i >= n4) return;
    float4 f = ((const float4*)in)[i];
    ushort4 o;
    o.x = f2bf(f.x); o.y = f2bf(f.y); o.z = f2bf(f.z); o.w = f2bf(f.w);
    ((ushort4*)out)[i] = o;
}

// ---------------- fp32 [R][C] -> bf16 [C][R] (tiled transpose) ----------------
__global__ void k_transpose(const float* __restrict__ in, unsigned short* __restrict__ out, int R, int C) {
    __shared__ float tile[32][33];
    int c0 = blockIdx.x * 32, r0 = blockIdx.y * 32;
    int tx = threadIdx.x, ty = threadIdx.y; // block (32,8)
#pragma unroll
    for (int i = 0; i < 4; ++i)
        tile[ty + i * 8][tx] = in[(size_t)(r0 + ty + i * 8) * C + c0 + tx];
    __syncthreads();
#pragma unroll
    for (int i = 0; i < 4; ++i)
        out[(size_t)(c0 + ty + i * 8) * R + r0 + tx] = f2bf(tile[tx][ty + i * 8]);
}

// ---------------- 128x128 bf16 MFMA GEMM core (m97-style staging) ----------
#define LDT 32

__device__ __forceinline__ void gemm_core(
    const unsigned short* __restrict__ A, const unsigned short* __restrict__ Bt,
    int K, unsigned short* As, unsigned short* Bs, f32x4 (&acc)[4][4])
{
    const int tid  = threadIdx.x;
    const int lane = tid & 63;
    const int w    = tid >> 6;
    const int wm   = (w >> 1) * 64, wn = (w & 1) * 64;
    const int l15  = lane & 15, quad = lane >> 4;
    const int m0 = blockIdx.x * 128, n0 = blockIdx.y * 128;

    const f32x4 zero = {0.f, 0.f, 0.f, 0.f};
#pragma unroll
    for (int i = 0; i < 4; ++i)
#pragma unroll
        for (int j = 0; j < 4; ++j) acc[i][j] = zero;

    const int r0 = tid >> 2, p8 = (tid & 3) * 8;
    const unsigned short* Ag0 = A  + (size_t)(m0 + r0) * K + p8;
    const unsigned short* Ag1 = A  + (size_t)(m0 + r0 + 64) * K + p8;
    const unsigned short* Bg0 = Bt + (size_t)(n0 + r0) * K + p8;
    const unsigned short* Bg1 = Bt + (size_t)(n0 + r0 + 64) * K + p8;
    unsigned short* lA0 = As + r0 * LDT + p8;          // byte offset tid*16
    unsigned short* lA1 = lA0 + 64 * LDT;
    unsigned short* lB0 = Bs + r0 * LDT + p8;
    unsigned short* lB1 = lB0 + 64 * LDT;

    const int nk = K >> 5;
    for (int kt = 0; kt < nk; ++kt) {
        __syncthreads();                    // LDS free (prev compute done)
        gld_lds16(Ag0, lA0);
        gld_lds16(Ag1, lA1);
        gld_lds16(Bg0, lB0);
        gld_lds16(Bg1, lB1);
        Ag0 += 32; Ag1 += 32; Bg0 += 32; Bg1 += 32;
        __syncthreads();                    // drains vmcnt -> data landed
        bf16x8 af[4], bfr[4];
#pragma unroll
        for (int mi = 0; mi < 4; ++mi)
            af[mi] = *(const bf16x8*)&As[(wm + mi * 16 + l15) * LDT + quad * 8];
#pragma unroll
        for (int nj = 0; nj < 4; ++nj)
            bfr[nj] = *(const bf16x8*)&Bs[(wn + nj * 16 + l15) * LDT + quad * 8];
#pragma unroll
        for (int mi = 0; mi < 4; ++mi)
#pragma unroll
            for (int nj = 0; nj < 4; ++nj)
                acc[mi][nj] = __builtin_amdgcn_mfma_f32_16x16x32_bf16(af[mi], bfr[nj], acc[mi][nj], 0, 0, 0);
    }
}

// QKV GEMM epilogue scatters into FRAGMENT-ORDER buffers so every attention
// global load is one coalesced 1024B block (base + lane*16B):
//  QL[bh][qi][m][h][lane][8]  : lane(l15,quad) holds Q[qi*32+16m+l15][32h+8quad+j]
//  KL[bh][t ][i][h][lane][8]  : lane holds K[64t+16i+l15][32h+8quad+j]
//  VL[bh][t ][dj][h][lane][8] : lane holds V[64t+32h+8quad+j][16dj+l15]
// Q pre-scaled by (1/8)*log2(e): softmax runs in exp2 domain.
__global__ __launch_bounds__(256) void k_gemm_qkv(
    const unsigned short* __restrict__ A, const unsigned short* __restrict__ Bt,
    const float* __restrict__ bias,
    unsigned short* __restrict__ QL, unsigned short* __restrict__ KL,
    unsigned short* __restrict__ VL)
{
    __shared__ __align__(16) unsigned short As[128 * LDT];
    __shared__ __align__(16) unsigned short Bs[128 * LDT];
    f32x4 acc[4][4];
    gemm_core(A, Bt, 768, As, Bs, acc);

    const int tid = threadIdx.x, lane = tid & 63, w = tid >> 6;
    const int wm = (w >> 1) * 64, wn = (w & 1) * 64;
    const int l15 = lane & 15, quad = lane >> 4;
    const int m0 = blockIdx.x * 128, n0 = blockIdx.y * 128;
    const float cscale = 0.18033688011f;  // (1/8) * log2(e)
#pragma unroll
    for (int nj = 0; nj < 4; ++nj) {
        int cg = n0 + wn + nj * 16 + l15;        // column in [0,2304)
        float bv = bias[cg];
        int which = cg / 768;                    // 0=q 1=k 2=v
        int rem = cg - which * 768;
        int hd = rem >> 6, d = rem & 63;
        float sc = (which == 0) ? cscale : 1.0f;
#pragma unroll
        for (int mi = 0; mi < 4; ++mi) {
#pragma unroll
            for (int r = 0; r < 4; ++r) {
                int rg = m0 + wm + mi * 16 + quad * 4 + r;   // row in [0,8192)
                int b = rg >> 12, tk = rg & 4095;
                int bh = b * 12 + hd;
                unsigned short ob = f2bf((acc[mi][nj][r] + bv) * sc);
                if (which == 0) {
                    size_t idx = ((((size_t)bh * 128 + (tk >> 5)) * 2 + ((tk >> 4) & 1)) * 2 + (d >> 5)) * 512
                               + ((d >> 3) & 3) * 128 + (tk & 15) * 8 + (d & 7);
                    QL[idx] = ob;
                } else if (which == 1) {
                    size_t idx = ((((size_t)bh * 64 + (tk >> 6)) * 4 + ((tk >> 4) & 3)) * 2 + (d >> 5)) * 512
                               + ((d >> 3) & 3) * 128 + (tk & 15) * 8 + (d & 7);
                    KL[idx] = ob;
                } else {
                    int wi = tk & 63;
                    size_t idx = ((((size_t)bh * 64 + (tk >> 6)) * 4 + (d >> 4)) * 2 + (wi >> 5)) * 512
                               + ((wi >> 3) & 3) * 128 + (d & 15) * 8 + (wi & 7);
                    VL[idx] = ob;
                }
            }
        }
    }
}

// Proj GEMM: A = y bf16 [8192][768], Bt = WprojT [768][768], out fp32 + bias
__global__ __launch_bounds__(256) void k_gemm_proj(
    const unsigned short* __restrict__ A, const unsigned short* __restrict__ Bt,
    const float* __restrict__ bias, float* __restrict__ out)
{
    __shared__ __align__(16) unsigned short As[128 * LDT];
    __shared__ __align__(16) unsigned short Bs[128 * LDT];
    f32x4 acc[4][4];
    gemm_core(A, Bt, 768, As, Bs, acc);

    const int tid = threadIdx.x, lane = tid & 63, w = tid >> 6;
    const int wm = (w >> 1) * 64, wn = (w & 1) * 64;
    const int l15 = lane & 15, quad = lane >> 4;
    const int m0 = blockIdx.x * 128, n0 = blockIdx.y * 128;
#pragma unroll
    for (int nj = 0; nj < 4; ++nj) {
        int cg = n0 + wn + nj * 16 + l15;
        float bv = bias[cg];
#pragma unroll
        for (int mi = 0; mi < 4; ++mi)
#pragma unroll
            for (int r = 0; r < 4; ++r) {
                int rg = m0 + wm + mi * 16 + quad * 4 + r;
                out[(size_t)rg * 768 + cg] = acc[mi][nj][r] + bv;
            }
    }
}

// ---------------- Flash attention, causal, split-K(2), XCD-local, PIPELINED --
// R2: back to the R0 structure (independent waves, no in-loop barrier; R1's
// lockstep split-Q regressed 100->137us: latency-bound, not L2-BW-bound).
// Change vs R0: 2-wave blocks (128 thr) instead of 4-wave. Residency cap is
// still 16 waves/CU (VGPR=112 binds), but per-CU assigned waves go 12->24
// with 8-block residency + a real queue -> HW scheduler rebalances as blocks
// drain (R0: only 12 blocks for 4 slots/CU, time-avg occupancy 19%).
// Combine halves (1 partial, not 3); LDS/block halves (17408 B).
// T5: s_setprio(1) around the MFMA clusters (attn +4-7%, m191 — requires
// independent waves per SIMD, which this structure has and R1's didn't).
// grid id = qidx*24 + bh => XCD = id%8 = bh%8: 3 heads/XCD, K+V set 3MB < L2.
// Software pipeline (one-iteration skew, P double-buffered in LDS):
//   iter kt: read P(kt) [written last iter] ; issue ka(kt+1) ;
//   l/O MFMAs (cover ka latency) ; issue vf(kt+1) ; QK(kt+1) ; exp2 (covers
//   vf latency) ; write P(kt+1) to other buffer.
// LDP=68 (136B rows): l15*34%32 = l15*2 -> conflict-free (R6: 0 conflicts).
#define LDP 68

__global__ __launch_bounds__(128, 4) void k_attn(
    const unsigned short* __restrict__ QL, const unsigned short* __restrict__ KL,
    const unsigned short* __restrict__ VL, unsigned short* __restrict__ Y)
{
    // P dbuf: 2 waves x 2 bufs x 32*LDP shorts = 17408B; combine buffer
    // (1 x 2560 floats = 10240B) has disjoint lifetime -> union.
    __shared__ __align__(16) char smem[17408];
    unsigned short* Ps = (unsigned short*)smem;
    float* Cb = (float*)smem;

    const int tid = threadIdx.x, lane = tid & 63;
    const int w = __builtin_amdgcn_readfirstlane(tid >> 6);   // wave-uniform, 0..1
    const int l15 = lane & 15, quad = lane >> 4;
    const int id = blockIdx.x;
    const int bh = id % 24;
    const int qi = 127 - id / 24;                     // longest first
    const int q0 = qi * 32;
    const int nkt = qi / 2 + 1;                       // 64-key tiles (causal)
    const int lo = (nkt * w) >> 1, hi = (nkt * (w + 1)) >> 1;
    unsigned short* Pw = Ps + w * 2 * 32 * LDP;       // this wave's two buffers

    const int pw_off = l15 * LDP + quad * 4;          // P write base (shorts)
    const int pr_off = l15 * LDP + quad * 8;          // P read base

    // fragment-chunk bases (each chunk = 512 shorts = 1024B, lane offset *8)
    const unsigned short* Qb = QL + (((size_t)bh * 128 + qi) * 4) * 512 + lane * 8;
    const unsigned short* kp = KL + ((size_t)bh * 64 + lo) * 4096 + lane * 8;
    const unsigned short* vp = VL + ((size_t)bh * 64 + lo) * 4096 + lane * 8;

    // Q^T B-fragments (chunk layout matches B-frag exactly)
    bf16x8 qt[2][2];
#pragma unroll
    for (int m = 0; m < 2; ++m)
#pragma unroll
        for (int h = 0; h < 2; ++h)
            qt[m][h] = *(const bf16x8*)(Qb + (m * 2 + h) * 512);

    const f32x4 zero = {0.f, 0.f, 0.f, 0.f};
    f32x4 O[2][4], lac[2];
#pragma unroll
    for (int m = 0; m < 2; ++m) {
        lac[m] = zero;
#pragma unroll
        for (int dj = 0; dj < 4; ++dj) O[m][dj] = zero;
    }

    const short ONE = (short)0x3F80;  // bf16 1.0
    const bf16x8 onesf = {ONE, ONE, ONE, ONE, ONE, ONE, ONE, ONE};

    if (lo < hi) {
        bf16x8 ka[4][2], vf[4][2];
#pragma unroll
        for (int i = 0; i < 4; ++i)
#pragma unroll
            for (int h = 0; h < 2; ++h)
                ka[i][h] = *(const bf16x8*)(kp + (i * 2 + h) * 512);
#pragma unroll
        for (int dj = 0; dj < 4; ++dj)
#pragma unroll
            for (int h = 0; h < 2; ++h)
                vf[dj][h] = *(const bf16x8*)(vp + (dj * 2 + h) * 512);

        // ---- prologue: st(lo) -> exp2 -> P buf0
        {
            f32x4 st[2][4];
#pragma unroll
            for (int i = 0; i < 4; ++i)
#pragma unroll
                for (int m = 0; m < 2; ++m) {
                    f32x4 z = __builtin_amdgcn_mfma_f32_16x16x32_bf16(ka[i][0], qt[m][0], zero, 0, 0, 0);
                    st[m][i] = __builtin_amdgcn_mfma_f32_16x16x32_bf16(ka[i][1], qt[m][1], z, 0, 0, 0);
                }
            if (lo == nkt - 1) {
                const int kb = lo * 64;
#pragma unroll
                for (int m = 0; m < 2; ++m)
#pragma unroll
                    for (int i = 0; i < 4; ++i)
#pragma unroll
                        for (int r = 0; r < 4; ++r)
                            if (kb + i * 16 + quad * 4 + r > q0 + m * 16 + l15)
                                st[m][i][r] = -INFINITY;
            }
#pragma unroll
            for (int m = 0; m < 2; ++m)
#pragma unroll
                for (int i = 0; i < 4; ++i) {
                    unsigned e0 = __float_as_uint(__builtin_amdgcn_exp2f(st[m][i][0])) + 0x8000u;
                    unsigned e1 = __float_as_uint(__builtin_amdgcn_exp2f(st[m][i][1])) + 0x8000u;
                    unsigned e2 = __float_as_uint(__builtin_amdgcn_exp2f(st[m][i][2])) + 0x8000u;
                    unsigned e3 = __float_as_uint(__builtin_amdgcn_exp2f(st[m][i][3])) + 0x8000u;
                    uint2 pk;
                    pk.x = __builtin_amdgcn_perm(e1, e0, 0x07060302);
                    pk.y = __builtin_amdgcn_perm(e3, e2, 0x07060302);
                    *(uint2*)(Pw + pw_off + m * 16 * LDP + i * 16) = pk;
                }
        }

        for (int kt = lo; kt < hi; ++kt) {
            unsigned short* bc = Pw + ((kt - lo) & 1) * 32 * LDP;
            unsigned short* bn = Pw + (((kt - lo) & 1) ^ 1) * 32 * LDP;
            const bool more = (kt + 1 < hi);

            // ---- read P(kt) as A-frags (written last iter; no RAW stall)
            bf16x8 pa[2][2];
#pragma unroll
            for (int m = 0; m < 2; ++m) {
                pa[m][0] = *(const bf16x8*)(bc + pr_off + m * 16 * LDP);
                pa[m][1] = *(const bf16x8*)(bc + pr_off + m * 16 * LDP + 32);
            }

            // ---- issue ka(kt+1) early; latency covered by l/O MFMAs below
            if (more) {
                kp += 4096;
#pragma unroll
                for (int i = 0; i < 4; ++i)
#pragma unroll
                    for (int h = 0; h < 2; ++h)
                        ka[i][h] = *(const bf16x8*)(kp + (i * 2 + h) * 512);
            }

            // ---- l += P @ ones ; O += P V(kt)   [T5: prio up in MFMA cluster]
            __builtin_amdgcn_s_setprio(1);
#pragma unroll
            for (int m = 0; m < 2; ++m) {
                f32x4 z = __builtin_amdgcn_mfma_f32_16x16x32_bf16(pa[m][0], onesf, lac[m], 0, 0, 0);
                lac[m] = __builtin_amdgcn_mfma_f32_16x16x32_bf16(pa[m][1], onesf, z, 0, 0, 0);
            }
#pragma unroll
            for (int dj = 0; dj < 4; ++dj)
#pragma unroll
                for (int m = 0; m < 2; ++m) {
                    f32x4 z = __builtin_amdgcn_mfma_f32_16x16x32_bf16(pa[m][0], vf[dj][0], O[m][dj], 0, 0, 0);
                    O[m][dj] = __builtin_amdgcn_mfma_f32_16x16x32_bf16(pa[m][1], vf[dj][1], z, 0, 0, 0);
                }
            __builtin_amdgcn_s_setprio(0);

            if (more) {
                // ---- issue vf(kt+1); latency covered by QK + exp2 below
                vp += 4096;
#pragma unroll
                for (int dj = 0; dj < 4; ++dj)
#pragma unroll
                    for (int h = 0; h < 2; ++h)
                        vf[dj][h] = *(const bf16x8*)(vp + (dj * 2 + h) * 512);

                // ---- st(kt+1) = K Q^T (ka latency already covered)
                __builtin_amdgcn_s_setprio(1);
                f32x4 st[2][4];
#pragma unroll
                for (int i = 0; i < 4; ++i)
#pragma unroll
                    for (int m = 0; m < 2; ++m) {
                        f32x4 z = __builtin_amdgcn_mfma_f32_16x16x32_bf16(ka[i][0], qt[m][0], zero, 0, 0, 0);
                        st[m][i] = __builtin_amdgcn_mfma_f32_16x16x32_bf16(ka[i][1], qt[m][1], z, 0, 0, 0);
                    }
                __builtin_amdgcn_s_setprio(0);
                if (kt + 1 == nkt - 1) {
                    const int kb = (kt + 1) * 64;
#pragma unroll
                    for (int m = 0; m < 2; ++m)
#pragma unroll
                        for (int i = 0; i < 4; ++i)
#pragma unroll
                            for (int r = 0; r < 4; ++r)
                                if (kb + i * 16 + quad * 4 + r > q0 + m * 16 + l15)
                                    st[m][i][r] = -INFINITY;
                }
                // ---- p = exp2(s); pack; write P(kt+1) to other buffer
#pragma unroll
                for (int m = 0; m < 2; ++m)
#pragma unroll
                    for (int i = 0; i < 4; ++i) {
                        unsigned e0 = __float_as_uint(__builtin_amdgcn_exp2f(st[m][i][0])) + 0x8000u;
                        unsigned e1 = __float_as_uint(__builtin_amdgcn_exp2f(st[m][i][1])) + 0x8000u;
                        unsigned e2 = __float_as_uint(__builtin_amdgcn_exp2f(st[m][i][2])) + 0x8000u;
                        unsigned e3 = __float_as_uint(__builtin_amdgcn_exp2f(st[m][i][3])) + 0x8000u;
                        uint2 pk;
                        pk.x = __builtin_amdgcn_perm(e1, e0, 0x07060302);
                        pk.y = __builtin_amdgcn_perm(e3, e2, 0x07060302);
                        *(uint2*)(bn + pw_off + m * 16 * LDP + i * 16) = pk;
                    }
            }
        }
    }

    // ---- combine the 2 partial (O,l) via LDS (additive: no max was used)
    __syncthreads();   // both waves done with their P regions
    if (w == 1) {
#pragma unroll
        for (int m = 0; m < 2; ++m) {
#pragma unroll
            for (int dj = 0; dj < 4; ++dj)
                *(f32x4*)&Cb[(m * 4 + dj) * 256 + lane * 4] = O[m][dj];
            *(f32x4*)&Cb[2048 + m * 256 + lane * 4] = lac[m];
        }
    }
    __syncthreads();
    if (w == 0) {
#pragma unroll
        for (int m = 0; m < 2; ++m) {
#pragma unroll
            for (int dj = 0; dj < 4; ++dj)
                O[m][dj] += *(const f32x4*)&Cb[(m * 4 + dj) * 256 + lane * 4];
            lac[m] += *(const f32x4*)&Cb[2048 + m * 256 + lane * 4];
        }
        // epilogue: O / l -> Y [b][t][h*64+d] bf16
        const int b = bh / 12, hd = bh % 12;
#pragma unroll
        for (int m = 0; m < 2; ++m)
#pragma unroll
            for (int r = 0; r < 4; ++r) {
                float inv = 1.0f / lac[m][r];
                int t = q0 + 16 * m + quad * 4 + r;
                size_t base = ((size_t)(b * 4096 + t)) * 768 + hd * 64;
#pragma unroll
                for (int dj = 0; dj < 4; ++dj)
                    Y[base + dj * 16 + l15] = f2bf(O[m][dj][r] * inv);
            }
    }
}

// ---------------- launch ----------------
extern "C" void kernel_launch(void* const* d_in, const int* in_sizes, int n_in,
                              void* d_out, int out_size, void* d_ws, size_t ws_size,
                              hipStream_t stream) {
    (void)in_sizes; (void)n_in; (void)out_size; (void)ws_size;
    const float* x     = (const float*)d_in[0];
    const float* Wqkv  = (const float*)d_in[1];
    const float* bqkv  = (const float*)d_in[2];
    const float* Wproj = (const float*)d_in[3];
    const float* bproj = (const float*)d_in[4];
    float* out = (float*)d_out;

    char* ws = (char*)d_ws;
    size_t off = 0;
    auto alloc = [&](size_t bytes) -> void* {
        void* p = ws + off;
        off += (bytes + 255) & ~(size_t)255;
        return p;
    };
    unsigned short* xb     = (unsigned short*)alloc((size_t)8192 * 768 * 2);
    unsigned short* WqkvT  = (unsigned short*)alloc((size_t)2304 * 768 * 2);
    unsigned short* WprojT = (unsigned short*)alloc((size_t)768 * 768 * 2);
    unsigned short* QLb    = (unsigned short*)alloc((size_t)24 * 4096 * 64 * 2);
    unsigned short* KLb    = (unsigned short*)alloc((size_t)24 * 4096 * 64 * 2);
    unsigned short* VLb    = (unsigned short*)alloc((size_t)24 * 4096 * 64 * 2);
    unsigned short* Yb     = (unsigned short*)alloc((size_t)8192 * 768 * 2);

    k_convert<<<6144, 256, 0, stream>>>(x, xb, 8192 * 768 / 4);
    dim3 tb(32, 8);
    k_transpose<<<dim3(72, 24), tb, 0, stream>>>(Wqkv, WqkvT, 768, 2304);
    k_transpose<<<dim3(24, 24), tb, 0, stream>>>(Wproj, WprojT, 768, 768);
    k_gemm_qkv<<<dim3(64, 18), 256, 0, stream>>>(xb, WqkvT, bqkv, QLb, KLb, VLb);
    k_attn<<<dim3(3072), 128, 0, stream>>>(QLb, KLb, VLb, Yb);
    k_gemm_proj<<<dim3(64, 6), 256, 0, stream>>>(Yb, WprojT, bproj, out);
}

// Round 3
// 251.310 us; speedup vs baseline: 1.6890x; 1.6890x over previous
//
#include <hip/hip_runtime.h>
#include <math.h>
#include <stdint.h>

// MFMA fragment types (guide §3, compile-verified on gfx950)
typedef __attribute__((ext_vector_type(8))) short bf16x8;   // 8 bf16 in 4 VGPRs
typedef __attribute__((ext_vector_type(4))) float f32x4;    // 4 fp32 acc

__device__ __forceinline__ unsigned short f2bf(float f) {
    union { float f; unsigned u; } v; v.f = f;
    return (unsigned short)((v.u + 0x7fffu + ((v.u >> 16) & 1u)) >> 16); // RNE
}

// async global->LDS, 16B per lane; LDS dest = firstlane base + lane*16 (m97)
__device__ __forceinline__ void gld_lds16(const void* g, void* l) {
    __builtin_amdgcn_global_load_lds(
        (const __attribute__((address_space(1))) unsigned*)(uintptr_t)g,
        (__attribute__((address_space(3))) unsigned*)(uintptr_t)l, 16, 0, 0);
}

// ---------------- fp32 -> bf16 elementwise (x4 vectorized) ----------------
__global__ void k_convert(const float* __restrict__ in, unsigned short* __restrict__ out, int n4) {
    int i = blockIdx.x * blockDim.x + threadIdx.x;
    if (i >= n4) return;
    float4 f = ((const float4*)in)[i];
    ushort4 o;
    o.x = f2bf(f.x); o.y = f2bf(f.y); o.z = f2bf(f.z); o.w = f2bf(f.w);
    ((ushort4*)out)[i] = o;
}

// ---------------- fp32 [R][C] -> bf16 [C][R] (tiled transpose) ----------------
__global__ void k_transpose(const float* __restrict__ in, unsigned short* __restrict__ out, int R, int C) {
    __shared__ float tile[32][33];
    int c0 = blockIdx.x * 32, r0 = blockIdx.y * 32;
    int tx = threadIdx.x, ty = threadIdx.y; // block (32,8)
#pragma unroll
    for (int i = 0; i < 4; ++i)
        tile[ty + i * 8][tx] = in[(size_t)(r0 + ty + i * 8) * C + c0 + tx];
    __syncthreads();
#pragma unroll
    for (int i = 0; i < 4; ++i)
        out[(size_t)(c0 + ty + i * 8) * R + r0 + tx] = f2bf(tile[tx][ty + i * 8]);
}

// ---------------- 128x128 bf16 MFMA GEMM core (m97-style staging) ----------
#define LDT 32

__device__ __forceinline__ void gemm_core(
    const unsigned short* __restrict__ A, const unsigned short* __restrict__ Bt,
    int K, unsigned short* As, unsigned short* Bs, f32x4 (&acc)[4][4])
{
    const int tid  = threadIdx.x;
    const int lane = tid & 63;
    const int w    = tid >> 6;
    const int wm   = (w >> 1) * 64, wn = (w & 1) * 64;
    const int l15  = lane & 15, quad = lane >> 4;
    const int m0 = blockIdx.x * 128, n0 = blockIdx.y * 128;

    const f32x4 zero = {0.f, 0.f, 0.f, 0.f};
#pragma unroll
    for (int i = 0; i < 4; ++i)
#pragma unroll
        for (int j = 0; j < 4; ++j) acc[i][j] = zero;

    const int r0 = tid >> 2, p8 = (tid & 3) * 8;
    const unsigned short* Ag0 = A  + (size_t)(m0 + r0) * K + p8;
    const unsigned short* Ag1 = A  + (size_t)(m0 + r0 + 64) * K + p8;
    const unsigned short* Bg0 = Bt + (size_t)(n0 + r0) * K + p8;
    const unsigned short* Bg1 = Bt + (size_t)(n0 + r0 + 64) * K + p8;
    unsigned short* lA0 = As + r0 * LDT + p8;          // byte offset tid*16
    unsigned short* lA1 = lA0 + 64 * LDT;
    unsigned short* lB0 = Bs + r0 * LDT + p8;
    unsigned short* lB1 = lB0 + 64 * LDT;

    const int nk = K >> 5;
    for (int kt = 0; kt < nk; ++kt) {
        __syncthreads();                    // LDS free (prev compute done)
        gld_lds16(Ag0, lA0);
        gld_lds16(Ag1, lA1);
        gld_lds16(Bg0, lB0);
        gld_lds16(Bg1, lB1);
        Ag0 += 32; Ag1 += 32; Bg0 += 32; Bg1 += 32;
        __syncthreads();                    // drains vmcnt -> data landed
        bf16x8 af[4], bfr[4];
#pragma unroll
        for (int mi = 0; mi < 4; ++mi)
            af[mi] = *(const bf16x8*)&As[(wm + mi * 16 + l15) * LDT + quad * 8];
#pragma unroll
        for (int nj = 0; nj < 4; ++nj)
            bfr[nj] = *(const bf16x8*)&Bs[(wn + nj * 16 + l15) * LDT + quad * 8];
#pragma unroll
        for (int mi = 0; mi < 4; ++mi)
#pragma unroll
            for (int nj = 0; nj < 4; ++nj)
                acc[mi][nj] = __builtin_amdgcn_mfma_f32_16x16x32_bf16(af[mi], bfr[nj], acc[mi][nj], 0, 0, 0);
    }
}

// QKV GEMM epilogue scatters into FRAGMENT-ORDER buffers so every attention
// global load is one coalesced 1024B block (base + lane*16B):
//  QL[bh][qi][m][h][lane][8]  : lane(l15,quad) holds Q[qi*32+16m+l15][32h+8quad+j]
//  KL[bh][t ][i][h][lane][8]  : lane holds K[64t+16i+l15][32h+8quad+j]
//  VL[bh][t ][dj][h][lane][8] : lane holds V[64t+32h+8quad+j][16dj+l15]
// Q pre-scaled by (1/8)*log2(e): softmax runs in exp2 domain.
__global__ __launch_bounds__(256) void k_gemm_qkv(
    const unsigned short* __restrict__ A, const unsigned short* __restrict__ Bt,
    const float* __restrict__ bias,
    unsigned short* __restrict__ QL, unsigned short* __restrict__ KL,
    unsigned short* __restrict__ VL)
{
    __shared__ __align__(16) unsigned short As[128 * LDT];
    __shared__ __align__(16) unsigned short Bs[128 * LDT];
    f32x4 acc[4][4];
    gemm_core(A, Bt, 768, As, Bs, acc);

    const int tid = threadIdx.x, lane = tid & 63, w = tid >> 6;
    const int wm = (w >> 1) * 64, wn = (w & 1) * 64;
    const int l15 = lane & 15, quad = lane >> 4;
    const int m0 = blockIdx.x * 128, n0 = blockIdx.y * 128;
    const float cscale = 0.18033688011f;  // (1/8) * log2(e)
#pragma unroll
    for (int nj = 0; nj < 4; ++nj) {
        int cg = n0 + wn + nj * 16 + l15;        // column in [0,2304)
        float bv = bias[cg];
        int which = cg / 768;                    // 0=q 1=k 2=v
        int rem = cg - which * 768;
        int hd = rem >> 6, d = rem & 63;
        float sc = (which == 0) ? cscale : 1.0f;
#pragma unroll
        for (int mi = 0; mi < 4; ++mi) {
#pragma unroll
            for (int r = 0; r < 4; ++r) {
                int rg = m0 + wm + mi * 16 + quad * 4 + r;   // row in [0,8192)
                int b = rg >> 12, tk = rg & 4095;
                int bh = b * 12 + hd;
                unsigned short ob = f2bf((acc[mi][nj][r] + bv) * sc);
                if (which == 0) {
                    size_t idx = ((((size_t)bh * 128 + (tk >> 5)) * 2 + ((tk >> 4) & 1)) * 2 + (d >> 5)) * 512
                               + ((d >> 3) & 3) * 128 + (tk & 15) * 8 + (d & 7);
                    QL[idx] = ob;
                } else if (which == 1) {
                    size_t idx = ((((size_t)bh * 64 + (tk >> 6)) * 4 + ((tk >> 4) & 3)) * 2 + (d >> 5)) * 512
                               + ((d >> 3) & 3) * 128 + (tk & 15) * 8 + (d & 7);
                    KL[idx] = ob;
                } else {
                    int wi = tk & 63;
                    size_t idx = ((((size_t)bh * 64 + (tk >> 6)) * 4 + (d >> 4)) * 2 + (wi >> 5)) * 512
                               + ((wi >> 3) & 3) * 128 + (d & 15) * 8 + (wi & 7);
                    VL[idx] = ob;
                }
            }
        }
    }
}

// Proj GEMM: A = y bf16 [8192][768], Bt = WprojT [768][768], out fp32 + bias
__global__ __launch_bounds__(256) void k_gemm_proj(
    const unsigned short* __restrict__ A, const unsigned short* __restrict__ Bt,
    const float* __restrict__ bias, float* __restrict__ out)
{
    __shared__ __align__(16) unsigned short As[128 * LDT];
    __shared__ __align__(16) unsigned short Bs[128 * LDT];
    f32x4 acc[4][4];
    gemm_core(A, Bt, 768, As, Bs, acc);

    const int tid = threadIdx.x, lane = tid & 63, w = tid >> 6;
    const int wm = (w >> 1) * 64, wn = (w & 1) * 64;
    const int l15 = lane & 15, quad = lane >> 4;
    const int m0 = blockIdx.x * 128, n0 = blockIdx.y * 128;
#pragma unroll
    for (int nj = 0; nj < 4; ++nj) {
        int cg = n0 + wn + nj * 16 + l15;
        float bv = bias[cg];
#pragma unroll
        for (int mi = 0; mi < 4; ++mi)
#pragma unroll
            for (int r = 0; r < 4; ++r) {
                int rg = m0 + wm + mi * 16 + quad * 4 + r;
                out[(size_t)rg * 768 + cg] = acc[mi][nj][r] + bv;
            }
    }
}

// ---------------- Flash attention, causal, split-K(2), XCD-local, PIPELINED --
// R3 = R2 minus the VGPR cap. R2's __launch_bounds__(128,4) forced VGPR=64 ->
// massive scratch spills (FETCH 449MB, WRITE 707MB, 55% HBM peak = spill pump,
// 267us). With plain __launch_bounds__(128) the compiler allocates ~112 VGPR;
// at 112 VGPR the HW fits 4 waves/SIMD -> 16 waves/CU -> 8 resident 2-wave
// blocks (vs R0's 3 four-wave blocks): deeper queue, scheduler rebalances as
// blocks drain; combine is 1 partial (not 3), LDS/block 17408B.
// T5 setprio around MFMA clusters kept (independent waves per SIMD regime).
// grid id = qidx*24 + bh => XCD = id%8 = bh%8: 3 heads/XCD, K+V set 3MB < L2.
// Software pipeline (one-iteration skew, P double-buffered in LDS):
//   iter kt: read P(kt) [written last iter] ; issue ka(kt+1) ;
//   l/O MFMAs (cover ka latency) ; issue vf(kt+1) ; QK(kt+1) ; exp2 (covers
//   vf latency) ; write P(kt+1) to other buffer.
// LDP=68 (136B rows): l15*34%32 = l15*2 -> conflict-free (R6: 0 conflicts).
#define LDP 68

__global__ __launch_bounds__(128) void k_attn(
    const unsigned short* __restrict__ QL, const unsigned short* __restrict__ KL,
    const unsigned short* __restrict__ VL, unsigned short* __restrict__ Y)
{
    // P dbuf: 2 waves x 2 bufs x 32*LDP shorts = 17408B; combine buffer
    // (1 x 2560 floats = 10240B) has disjoint lifetime -> union.
    __shared__ __align__(16) char smem[17408];
    unsigned short* Ps = (unsigned short*)smem;
    float* Cb = (float*)smem;

    const int tid = threadIdx.x, lane = tid & 63;
    const int w = __builtin_amdgcn_readfirstlane(tid >> 6);   // wave-uniform, 0..1
    const int l15 = lane & 15, quad = lane >> 4;
    const int id = blockIdx.x;
    const int bh = id % 24;
    const int qi = 127 - id / 24;                     // longest first
    const int q0 = qi * 32;
    const int nkt = qi / 2 + 1;                       // 64-key tiles (causal)
    const int lo = (nkt * w) >> 1, hi = (nkt * (w + 1)) >> 1;
    unsigned short* Pw = Ps + w * 2 * 32 * LDP;       // this wave's two buffers

    const int pw_off = l15 * LDP + quad * 4;          // P write base (shorts)
    const int pr_off = l15 * LDP + quad * 8;          // P read base

    // fragment-chunk bases (each chunk = 512 shorts = 1024B, lane offset *8)
    const unsigned short* Qb = QL + (((size_t)bh * 128 + qi) * 4) * 512 + lane * 8;
    const unsigned short* kp = KL + ((size_t)bh * 64 + lo) * 4096 + lane * 8;
    const unsigned short* vp = VL + ((size_t)bh * 64 + lo) * 4096 + lane * 8;

    // Q^T B-fragments (chunk layout matches B-frag exactly)
    bf16x8 qt[2][2];
#pragma unroll
    for (int m = 0; m < 2; ++m)
#pragma unroll
        for (int h = 0; h < 2; ++h)
            qt[m][h] = *(const bf16x8*)(Qb + (m * 2 + h) * 512);

    const f32x4 zero = {0.f, 0.f, 0.f, 0.f};
    f32x4 O[2][4], lac[2];
#pragma unroll
    for (int m = 0; m < 2; ++m) {
        lac[m] = zero;
#pragma unroll
        for (int dj = 0; dj < 4; ++dj) O[m][dj] = zero;
    }

    const short ONE = (short)0x3F80;  // bf16 1.0
    const bf16x8 onesf = {ONE, ONE, ONE, ONE, ONE, ONE, ONE, ONE};

    if (lo < hi) {
        bf16x8 ka[4][2], vf[4][2];
#pragma unroll
        for (int i = 0; i < 4; ++i)
#pragma unroll
            for (int h = 0; h < 2; ++h)
                ka[i][h] = *(const bf16x8*)(kp + (i * 2 + h) * 512);
#pragma unroll
        for (int dj = 0; dj < 4; ++dj)
#pragma unroll
            for (int h = 0; h < 2; ++h)
                vf[dj][h] = *(const bf16x8*)(vp + (dj * 2 + h) * 512);

        // ---- prologue: st(lo) -> exp2 -> P buf0
        {
            f32x4 st[2][4];
#pragma unroll
            for (int i = 0; i < 4; ++i)
#pragma unroll
                for (int m = 0; m < 2; ++m) {
                    f32x4 z = __builtin_amdgcn_mfma_f32_16x16x32_bf16(ka[i][0], qt[m][0], zero, 0, 0, 0);
                    st[m][i] = __builtin_amdgcn_mfma_f32_16x16x32_bf16(ka[i][1], qt[m][1], z, 0, 0, 0);
                }
            if (lo == nkt - 1) {
                const int kb = lo * 64;
#pragma unroll
                for (int m = 0; m < 2; ++m)
#pragma unroll
                    for (int i = 0; i < 4; ++i)
#pragma unroll
                        for (int r = 0; r < 4; ++r)
                            if (kb + i * 16 + quad * 4 + r > q0 + m * 16 + l15)
                                st[m][i][r] = -INFINITY;
            }
#pragma unroll
            for (int m = 0; m < 2; ++m)
#pragma unroll
                for (int i = 0; i < 4; ++i) {
                    unsigned e0 = __float_as_uint(__builtin_amdgcn_exp2f(st[m][i][0])) + 0x8000u;
                    unsigned e1 = __float_as_uint(__builtin_amdgcn_exp2f(st[m][i][1])) + 0x8000u;
                    unsigned e2 = __float_as_uint(__builtin_amdgcn_exp2f(st[m][i][2])) + 0x8000u;
                    unsigned e3 = __float_as_uint(__builtin_amdgcn_exp2f(st[m][i][3])) + 0x8000u;
                    uint2 pk;
                    pk.x = __builtin_amdgcn_perm(e1, e0, 0x07060302);
                    pk.y = __builtin_amdgcn_perm(e3, e2, 0x07060302);
                    *(uint2*)(Pw + pw_off + m * 16 * LDP + i * 16) = pk;
                }
        }

        for (int kt = lo; kt < hi; ++kt) {
            unsigned short* bc = Pw + ((kt - lo) & 1) * 32 * LDP;
            unsigned short* bn = Pw + (((kt - lo) & 1) ^ 1) * 32 * LDP;
            const bool more = (kt + 1 < hi);

            // ---- read P(kt) as A-frags (written last iter; no RAW stall)
            bf16x8 pa[2][2];
#pragma unroll
            for (int m = 0; m < 2; ++m) {
                pa[m][0] = *(const bf16x8*)(bc + pr_off + m * 16 * LDP);
                pa[m][1] = *(const bf16x8*)(bc + pr_off + m * 16 * LDP + 32);
            }

            // ---- issue ka(kt+1) early; latency covered by l/O MFMAs below
            if (more) {
                kp += 4096;
#pragma unroll
                for (int i = 0; i < 4; ++i)
#pragma unroll
                    for (int h = 0; h < 2; ++h)
                        ka[i][h] = *(const bf16x8*)(kp + (i * 2 + h) * 512);
            }

            // ---- l += P @ ones ; O += P V(kt)   [T5: prio up in MFMA cluster]
            __builtin_amdgcn_s_setprio(1);
#pragma unroll
            for (int m = 0; m < 2; ++m) {
                f32x4 z = __builtin_amdgcn_mfma_f32_16x16x32_bf16(pa[m][0], onesf, lac[m], 0, 0, 0);
                lac[m] = __builtin_amdgcn_mfma_f32_16x16x32_bf16(pa[m][1], onesf, z, 0, 0, 0);
            }
#pragma unroll
            for (int dj = 0; dj < 4; ++dj)
#pragma unroll
                for (int m = 0; m < 2; ++m) {
                    f32x4 z = __builtin_amdgcn_mfma_f32_16x16x32_bf16(pa[m][0], vf[dj][0], O[m][dj], 0, 0, 0);
                    O[m][dj] = __builtin_amdgcn_mfma_f32_16x16x32_bf16(pa[m][1], vf[dj][1], z, 0, 0, 0);
                }
            __builtin_amdgcn_s_setprio(0);

            if (more) {
                // ---- issue vf(kt+1); latency covered by QK + exp2 below
                vp += 4096;
#pragma unroll
                for (int dj = 0; dj < 4; ++dj)
#pragma unroll
                    for (int h = 0; h < 2; ++h)
                        vf[dj][h] = *(const bf16x8*)(vp + (dj * 2 + h) * 512);

                // ---- st(kt+1) = K Q^T (ka latency already covered)
                __builtin_amdgcn_s_setprio(1);
                f32x4 st[2][4];
#pragma unroll
                for (int i = 0; i < 4; ++i)
#pragma unroll
                    for (int m = 0; m < 2; ++m) {
                        f32x4 z = __builtin_amdgcn_mfma_f32_16x16x32_bf16(ka[i][0], qt[m][0], zero, 0, 0, 0);
                        st[m][i] = __builtin_amdgcn_mfma_f32_16x16x32_bf16(ka[i][1], qt[m][1], z, 0, 0, 0);
                    }
                __builtin_amdgcn_s_setprio(0);
                if (kt + 1 == nkt - 1) {
                    const int kb = (kt + 1) * 64;
#pragma unroll
                    for (int m = 0; m < 2; ++m)
#pragma unroll
                        for (int i = 0; i < 4; ++i)
#pragma unroll
                            for (int r = 0; r < 4; ++r)
                                if (kb + i * 16 + quad * 4 + r > q0 + m * 16 + l15)
                                    st[m][i][r] = -INFINITY;
                }
                // ---- p = exp2(s); pack; write P(kt+1) to other buffer
#pragma unroll
                for (int m = 0; m < 2; ++m)
#pragma unroll
                    for (int i = 0; i < 4; ++i) {
                        unsigned e0 = __float_as_uint(__builtin_amdgcn_exp2f(st[m][i][0])) + 0x8000u;
                        unsigned e1 = __float_as_uint(__builtin_amdgcn_exp2f(st[m][i][1])) + 0x8000u;
                        unsigned e2 = __float_as_uint(__builtin_amdgcn_exp2f(st[m][i][2])) + 0x8000u;
                        unsigned e3 = __float_as_uint(__builtin_amdgcn_exp2f(st[m][i][3])) + 0x8000u;
                        uint2 pk;
                        pk.x = __builtin_amdgcn_perm(e1, e0, 0x07060302);
                        pk.y = __builtin_amdgcn_perm(e3, e2, 0x07060302);
                        *(uint2*)(bn + pw_off + m * 16 * LDP + i * 16) = pk;
                    }
            }
        }
    }

    // ---- combine the 2 partial (O,l) via LDS (additive: no max was used)
    __syncthreads();   // both waves done with their P regions
    if (w == 1) {
#pragma unroll
        for (int m = 0; m < 2; ++m) {
#pragma unroll
            for (int dj = 0; dj < 4; ++dj)
                *(f32x4*)&Cb[(m * 4 + dj) * 256 + lane * 4] = O[m][dj];
            *(f32x4*)&Cb[2048 + m * 256 + lane * 4] = lac[m];
        }
    }
    __syncthreads();
    if (w == 0) {
#pragma unroll
        for (int m = 0; m < 2; ++m) {
#pragma unroll
            for (int dj = 0; dj < 4; ++dj)
                O[m][dj] += *(const f32x4*)&Cb[(m * 4 + dj) * 256 + lane * 4];
            lac[m] += *(const f32x4*)&Cb[2048 + m * 256 + lane * 4];
        }
        // epilogue: O / l -> Y [b][t][h*64+d] bf16
        const int b = bh / 12, hd = bh % 12;
#pragma unroll
        for (int m = 0; m < 2; ++m)
#pragma unroll
            for (int r = 0; r < 4; ++r) {
                float inv = 1.0f / lac[m][r];
                int t = q0 + 16 * m + quad * 4 + r;
                size_t base = ((size_t)(b * 4096 + t)) * 768 + hd * 64;
#pragma unroll
                for (int dj = 0; dj < 4; ++dj)
                    Y[base + dj * 16 + l15] = f2bf(O[m][dj][r] * inv);
            }
    }
}

// ---------------- launch ----------------
extern "C" void kernel_launch(void* const* d_in, const int* in_sizes, int n_in,
                              void* d_out, int out_size, void* d_ws, size_t ws_size,
                              hipStream_t stream) {
    (void)in_sizes; (void)n_in; (void)out_size; (void)ws_size;
    const float* x     = (const float*)d_in[0];
    const float* Wqkv  = (const float*)d_in[1];
    const float* bqkv  = (const float*)d_in[2];
    const float* Wproj = (const float*)d_in[3];
    const float* bproj = (const float*)d_in[4];
    float* out = (float*)d_out;

    char* ws = (char*)d_ws;
    size_t off = 0;
    auto alloc = [&](size_t bytes) -> void* {
        void* p = ws + off;
        off += (bytes + 255) & ~(size_t)255;
        return p;
    };
    unsigned short* xb     = (unsigned short*)alloc((size_t)8192 * 768 * 2);
    unsigned short* WqkvT  = (unsigned short*)alloc((size_t)2304 * 768 * 2);
    unsigned short* WprojT = (unsigned short*)alloc((size_t)768 * 768 * 2);
    unsigned short* QLb    = (unsigned short*)alloc((size_t)24 * 4096 * 64 * 2);
    unsigned short* KLb    = (unsigned short*)alloc((size_t)24 * 4096 * 64 * 2);
    unsigned short* VLb    = (unsigned short*)alloc((size_t)24 * 4096 * 64 * 2);
    unsigned short* Yb     = (unsigned short*)alloc((size_t)8192 * 768 * 2);

    k_convert<<<6144, 256, 0, stream>>>(x, xb, 8192 * 768 / 4);
    dim3 tb(32, 8);
    k_transpose<<<dim3(72, 24), tb, 0, stream>>>(Wqkv, WqkvT, 768, 2304);
    k_transpose<<<dim3(24, 24), tb, 0, stream>>>(Wproj, WprojT, 768, 768);
    k_gemm_qkv<<<dim3(64, 18), 256, 0, stream>>>(xb, WqkvT, bqkv, QLb, KLb, VLb);
    k_attn<<<dim3(3072), 128, 0, stream>>>(QLb, KLb, VLb, Yb);
    k_gemm_proj<<<dim3(64, 6), 256, 0, stream>>>(Yb, WprojT, bproj, out);
}

// Round 4
// 246.196 us; speedup vs baseline: 1.7240x; 1.0208x over previous
//
#include <hip/hip_runtime.h>
#include <math.h>
#include <stdint.h>

// MFMA fragment types (guide §3, compile-verified on gfx950)
typedef __attribute__((ext_vector_type(8))) short bf16x8;   // 8 bf16 in 4 VGPRs
typedef __attribute__((ext_vector_type(4))) float f32x4;    // 4 fp32 acc

__device__ __forceinline__ unsigned short f2bf(float f) {
    union { float f; unsigned u; } v; v.f = f;
    return (unsigned short)((v.u + 0x7fffu + ((v.u >> 16) & 1u)) >> 16); // RNE
}

// async global->LDS, 16B per lane; LDS dest = firstlane base + lane*16 (m97)
__device__ __forceinline__ void gld_lds16(const void* g, void* l) {
    __builtin_amdgcn_global_load_lds(
        (const __attribute__((address_space(1))) unsigned*)(uintptr_t)g,
        (__attribute__((address_space(3))) unsigned*)(uintptr_t)l, 16, 0, 0);
}

// ---------------- fp32 -> bf16 elementwise (x4 vectorized) ----------------
__global__ void k_convert(const float* __restrict__ in, unsigned short* __restrict__ out, int n4) {
    int i = blockIdx.x * blockDim.x + threadIdx.x;
    if (i >= n4) return;
    float4 f = ((const float4*)in)[i];
    ushort4 o;
    o.x = f2bf(f.x); o.y = f2bf(f.y); o.z = f2bf(f.z); o.w = f2bf(f.w);
    ((ushort4*)out)[i] = o;
}

// ---------------- fp32 [R][C] -> bf16 [C][R] (tiled transpose) ----------------
__global__ void k_transpose(const float* __restrict__ in, unsigned short* __restrict__ out, int R, int C) {
    __shared__ float tile[32][33];
    int c0 = blockIdx.x * 32, r0 = blockIdx.y * 32;
    int tx = threadIdx.x, ty = threadIdx.y; // block (32,8)
#pragma unroll
    for (int i = 0; i < 4; ++i)
        tile[ty + i * 8][tx] = in[(size_t)(r0 + ty + i * 8) * C + c0 + tx];
    __syncthreads();
#pragma unroll
    for (int i = 0; i < 4; ++i)
        out[(size_t)(c0 + ty + i * 8) * R + r0 + tx] = f2bf(tile[tx][ty + i * 8]);
}

// ---------------- 128x128 bf16 MFMA GEMM core (m97-style staging) ----------
#define LDT 32

__device__ __forceinline__ void gemm_core(
    const unsigned short* __restrict__ A, const unsigned short* __restrict__ Bt,
    int K, unsigned short* As, unsigned short* Bs, f32x4 (&acc)[4][4])
{
    const int tid  = threadIdx.x;
    const int lane = tid & 63;
    const int w    = tid >> 6;
    const int wm   = (w >> 1) * 64, wn = (w & 1) * 64;
    const int l15  = lane & 15, quad = lane >> 4;
    const int m0 = blockIdx.x * 128, n0 = blockIdx.y * 128;

    const f32x4 zero = {0.f, 0.f, 0.f, 0.f};
#pragma unroll
    for (int i = 0; i < 4; ++i)
#pragma unroll
        for (int j = 0; j < 4; ++j) acc[i][j] = zero;

    const int r0 = tid >> 2, p8 = (tid & 3) * 8;
    const unsigned short* Ag0 = A  + (size_t)(m0 + r0) * K + p8;
    const unsigned short* Ag1 = A  + (size_t)(m0 + r0 + 64) * K + p8;
    const unsigned short* Bg0 = Bt + (size_t)(n0 + r0) * K + p8;
    const unsigned short* Bg1 = Bt + (size_t)(n0 + r0 + 64) * K + p8;
    unsigned short* lA0 = As + r0 * LDT + p8;          // byte offset tid*16
    unsigned short* lA1 = lA0 + 64 * LDT;
    unsigned short* lB0 = Bs + r0 * LDT + p8;
    unsigned short* lB1 = lB0 + 64 * LDT;

    const int nk = K >> 5;
    for (int kt = 0; kt < nk; ++kt) {
        __syncthreads();                    // LDS free (prev compute done)
        gld_lds16(Ag0, lA0);
        gld_lds16(Ag1, lA1);
        gld_lds16(Bg0, lB0);
        gld_lds16(Bg1, lB1);
        Ag0 += 32; Ag1 += 32; Bg0 += 32; Bg1 += 32;
        __syncthreads();                    // drains vmcnt -> data landed
        bf16x8 af[4], bfr[4];
#pragma unroll
        for (int mi = 0; mi < 4; ++mi)
            af[mi] = *(const bf16x8*)&As[(wm + mi * 16 + l15) * LDT + quad * 8];
#pragma unroll
        for (int nj = 0; nj < 4; ++nj)
            bfr[nj] = *(const bf16x8*)&Bs[(wn + nj * 16 + l15) * LDT + quad * 8];
#pragma unroll
        for (int mi = 0; mi < 4; ++mi)
#pragma unroll
            for (int nj = 0; nj < 4; ++nj)
                acc[mi][nj] = __builtin_amdgcn_mfma_f32_16x16x32_bf16(af[mi], bfr[nj], acc[mi][nj], 0, 0, 0);
    }
}

// QKV GEMM epilogue scatters into FRAGMENT-ORDER buffers so every attention
// global load is one coalesced 1024B block (base + lane*16B):
//  QL[bh][qi][m][h][lane][8]  : lane(l15,quad) holds Q[qi*32+16m+l15][32h+8quad+j]
//  KL[bh][t ][i][h][lane][8]  : lane holds K[64t+16i+l15][32h+8quad+j]
//  VL[bh][t ][dj][h][lane][8] : lane holds V[64t+32h+8quad+j][16dj+l15]
// Q pre-scaled by (1/8)*log2(e): softmax runs in exp2 domain.
__global__ __launch_bounds__(256) void k_gemm_qkv(
    const unsigned short* __restrict__ A, const unsigned short* __restrict__ Bt,
    const float* __restrict__ bias,
    unsigned short* __restrict__ QL, unsigned short* __restrict__ KL,
    unsigned short* __restrict__ VL)
{
    __shared__ __align__(16) unsigned short As[128 * LDT];
    __shared__ __align__(16) unsigned short Bs[128 * LDT];
    f32x4 acc[4][4];
    gemm_core(A, Bt, 768, As, Bs, acc);

    const int tid = threadIdx.x, lane = tid & 63, w = tid >> 6;
    const int wm = (w >> 1) * 64, wn = (w & 1) * 64;
    const int l15 = lane & 15, quad = lane >> 4;
    const int m0 = blockIdx.x * 128, n0 = blockIdx.y * 128;
    const float cscale = 0.18033688011f;  // (1/8) * log2(e)
#pragma unroll
    for (int nj = 0; nj < 4; ++nj) {
        int cg = n0 + wn + nj * 16 + l15;        // column in [0,2304)
        float bv = bias[cg];
        int which = cg / 768;                    // 0=q 1=k 2=v
        int rem = cg - which * 768;
        int hd = rem >> 6, d = rem & 63;
        float sc = (which == 0) ? cscale : 1.0f;
#pragma unroll
        for (int mi = 0; mi < 4; ++mi) {
#pragma unroll
            for (int r = 0; r < 4; ++r) {
                int rg = m0 + wm + mi * 16 + quad * 4 + r;   // row in [0,8192)
                int b = rg >> 12, tk = rg & 4095;
                int bh = b * 12 + hd;
                unsigned short ob = f2bf((acc[mi][nj][r] + bv) * sc);
                if (which == 0) {
                    size_t idx = ((((size_t)bh * 128 + (tk >> 5)) * 2 + ((tk >> 4) & 1)) * 2 + (d >> 5)) * 512
                               + ((d >> 3) & 3) * 128 + (tk & 15) * 8 + (d & 7);
                    QL[idx] = ob;
                } else if (which == 1) {
                    size_t idx = ((((size_t)bh * 64 + (tk >> 6)) * 4 + ((tk >> 4) & 3)) * 2 + (d >> 5)) * 512
                               + ((d >> 3) & 3) * 128 + (tk & 15) * 8 + (d & 7);
                    KL[idx] = ob;
                } else {
                    int wi = tk & 63;
                    size_t idx = ((((size_t)bh * 64 + (tk >> 6)) * 4 + (d >> 4)) * 2 + (wi >> 5)) * 512
                               + ((wi >> 3) & 3) * 128 + (d & 15) * 8 + (wi & 7);
                    VL[idx] = ob;
                }
            }
        }
    }
}

// Proj GEMM: A = y bf16 [8192][768], Bt = WprojT [768][768], out fp32 + bias
__global__ __launch_bounds__(256) void k_gemm_proj(
    const unsigned short* __restrict__ A, const unsigned short* __restrict__ Bt,
    const float* __restrict__ bias, float* __restrict__ out)
{
    __shared__ __align__(16) unsigned short As[128 * LDT];
    __shared__ __align__(16) unsigned short Bs[128 * LDT];
    f32x4 acc[4][4];
    gemm_core(A, Bt, 768, As, Bs, acc);

    const int tid = threadIdx.x, lane = tid & 63, w = tid >> 6;
    const int wm = (w >> 1) * 64, wn = (w & 1) * 64;
    const int l15 = lane & 15, quad = lane >> 4;
    const int m0 = blockIdx.x * 128, n0 = blockIdx.y * 128;
#pragma unroll
    for (int nj = 0; nj < 4; ++nj) {
        int cg = n0 + wn + nj * 16 + l15;
        float bv = bias[cg];
#pragma unroll
        for (int mi = 0; mi < 4; ++mi)
#pragma unroll
            for (int r = 0; r < 4; ++r) {
                int rg = m0 + wm + mi * 16 + quad * 4 + r;
                out[(size_t)rg * 768 + cg] = acc[mi][nj][r] + bv;
            }
    }
}

// ---------------- Flash attention, causal, PAIRED-Q, XCD-local, PIPELINED ----
// R4: attack the per-CU L1-miss bandwidth wall found in R3 (29 B/cyc/CU:
// split-K waves each stream 16KB/iter of UNIQUE K/V; all K/V accesses miss
// the 32KB L1 since the per-XCD set is 3MB; everything stalls at ~50%).
// Fix: the 2 waves of a block take ADJACENT q-tiles {2g, 2g+1} and iterate
// the SAME key tiles 0..g. nkt(2g) == nkt(2g+1) == g+1, so both waves run
// IDENTICAL-length, identical-address loops launched together -> they stay
// within ~1 iter of each other WITHOUT any barrier; L1 (32KB ~ 2 iters of
// K+V) turns the trailing wave's loads into hits/MSHR-merges -> per-CU
// unique traffic halves. Worst case (drift) degenerates to R3 behavior.
// Split-K combine is GONE: each wave owns a full softmax and its 32 rows.
// Causal: only tile kt==g needs masking (wave0 wastes the upper 32 keys of
// that one tile, ~0.8% total; exp2(-inf)=0 keeps it exact).
// grid id = (63-g)*24 + bh (longest first); id%8 = bh%8 -> XCD-local K/V,
// 3 heads/XCD, K+V set 3MB < 4MB L2.
// Software pipeline (one-iteration skew, P double-buffered in LDS):
//   iter kt: read P(kt) [written last iter] ; issue ka(kt+1) ;
//   l/O MFMAs (cover ka latency) ; issue vf(kt+1) ; QK(kt+1) ; exp2 (covers
//   vf latency) ; write P(kt+1) to other buffer.
// LDP=68 (136B rows): l15*34%32 = l15*2 -> conflict-free (0 conflicts).
#define LDP 68

__global__ __launch_bounds__(128) void k_attn(
    const unsigned short* __restrict__ QL, const unsigned short* __restrict__ KL,
    const unsigned short* __restrict__ VL, unsigned short* __restrict__ Y)
{
    // P dbuf: 2 waves x 2 bufs x 32*LDP shorts = 17408B (wave-private)
    __shared__ __align__(16) char smem[17408];
    unsigned short* Ps = (unsigned short*)smem;

    const int tid = threadIdx.x, lane = tid & 63;
    const int w = __builtin_amdgcn_readfirstlane(tid >> 6);   // wave-uniform, 0..1
    const int l15 = lane & 15, quad = lane >> 4;
    const int id = blockIdx.x;
    const int bh = id % 24;                   // id%8 = bh%8 -> XCD-local K/V
    const int g  = 63 - id / 24;              // longest first, g in [0,64)
    const int qi = 2 * g + w;                 // this wave's 32-row q-tile
    const int q0 = qi * 32;
    const int nkt = g + 1;                    // key tiles; SAME for both waves
    unsigned short* Pw = Ps + w * 2 * 32 * LDP;   // this wave's two buffers

    const int pw_off = l15 * LDP + quad * 4;  // P write base (shorts)
    const int pr_off = l15 * LDP + quad * 8;  // P read base

    // fragment-chunk bases (each chunk = 512 shorts = 1024B, lane offset *8)
    const unsigned short* Qb = QL + (((size_t)bh * 128 + qi) * 4) * 512 + lane * 8;
    const unsigned short* kp = KL + ((size_t)bh * 64) * 4096 + lane * 8;
    const unsigned short* vp = VL + ((size_t)bh * 64) * 4096 + lane * 8;

    // Q^T B-fragments (chunk layout matches B-frag exactly)
    bf16x8 qt[2][2];
#pragma unroll
    for (int m = 0; m < 2; ++m)
#pragma unroll
        for (int h = 0; h < 2; ++h)
            qt[m][h] = *(const bf16x8*)(Qb + (m * 2 + h) * 512);

    const f32x4 zero = {0.f, 0.f, 0.f, 0.f};
    f32x4 O[2][4], lac[2];
#pragma unroll
    for (int m = 0; m < 2; ++m) {
        lac[m] = zero;
#pragma unroll
        for (int dj = 0; dj < 4; ++dj) O[m][dj] = zero;
    }

    const short ONE = (short)0x3F80;  // bf16 1.0
    const bf16x8 onesf = {ONE, ONE, ONE, ONE, ONE, ONE, ONE, ONE};

    bf16x8 ka[4][2], vf[4][2];
#pragma unroll
    for (int i = 0; i < 4; ++i)
#pragma unroll
        for (int h = 0; h < 2; ++h)
            ka[i][h] = *(const bf16x8*)(kp + (i * 2 + h) * 512);
#pragma unroll
    for (int dj = 0; dj < 4; ++dj)
#pragma unroll
        for (int h = 0; h < 2; ++h)
            vf[dj][h] = *(const bf16x8*)(vp + (dj * 2 + h) * 512);

    // ---- prologue: st(0) -> exp2 -> P buf0
    {
        f32x4 st[2][4];
#pragma unroll
        for (int i = 0; i < 4; ++i)
#pragma unroll
            for (int m = 0; m < 2; ++m) {
                f32x4 z = __builtin_amdgcn_mfma_f32_16x16x32_bf16(ka[i][0], qt[m][0], zero, 0, 0, 0);
                st[m][i] = __builtin_amdgcn_mfma_f32_16x16x32_bf16(ka[i][1], qt[m][1], z, 0, 0, 0);
            }
        if (nkt == 1) {                 // tile 0 is the diagonal tile
#pragma unroll
            for (int m = 0; m < 2; ++m)
#pragma unroll
                for (int i = 0; i < 4; ++i)
#pragma unroll
                    for (int r = 0; r < 4; ++r)
                        if (i * 16 + quad * 4 + r > q0 + m * 16 + l15)
                            st[m][i][r] = -INFINITY;
        }
#pragma unroll
        for (int m = 0; m < 2; ++m)
#pragma unroll
            for (int i = 0; i < 4; ++i) {
                unsigned e0 = __float_as_uint(__builtin_amdgcn_exp2f(st[m][i][0])) + 0x8000u;
                unsigned e1 = __float_as_uint(__builtin_amdgcn_exp2f(st[m][i][1])) + 0x8000u;
                unsigned e2 = __float_as_uint(__builtin_amdgcn_exp2f(st[m][i][2])) + 0x8000u;
                unsigned e3 = __float_as_uint(__builtin_amdgcn_exp2f(st[m][i][3])) + 0x8000u;
                uint2 pk;
                pk.x = __builtin_amdgcn_perm(e1, e0, 0x07060302);
                pk.y = __builtin_amdgcn_perm(e3, e2, 0x07060302);
                *(uint2*)(Pw + pw_off + m * 16 * LDP + i * 16) = pk;
            }
    }

    for (int kt = 0; kt < nkt; ++kt) {
        unsigned short* bc = Pw + (kt & 1) * 32 * LDP;
        unsigned short* bn = Pw + ((kt & 1) ^ 1) * 32 * LDP;
        const bool more = (kt + 1 < nkt);

        // ---- read P(kt) as A-frags (written last iter; no RAW stall)
        bf16x8 pa[2][2];
#pragma unroll
        for (int m = 0; m < 2; ++m) {
            pa[m][0] = *(const bf16x8*)(bc + pr_off + m * 16 * LDP);
            pa[m][1] = *(const bf16x8*)(bc + pr_off + m * 16 * LDP + 32);
        }

        // ---- issue ka(kt+1) early; latency covered by l/O MFMAs below
        if (more) {
            kp += 4096;
#pragma unroll
            for (int i = 0; i < 4; ++i)
#pragma unroll
                for (int h = 0; h < 2; ++h)
                    ka[i][h] = *(const bf16x8*)(kp + (i * 2 + h) * 512);
        }

        // ---- l += P @ ones ; O += P V(kt)   [T5: prio up in MFMA cluster]
        __builtin_amdgcn_s_setprio(1);
#pragma unroll
        for (int m = 0; m < 2; ++m) {
            f32x4 z = __builtin_amdgcn_mfma_f32_16x16x32_bf16(pa[m][0], onesf, lac[m], 0, 0, 0);
            lac[m] = __builtin_amdgcn_mfma_f32_16x16x32_bf16(pa[m][1], onesf, z, 0, 0, 0);
        }
#pragma unroll
        for (int dj = 0; dj < 4; ++dj)
#pragma unroll
            for (int m = 0; m < 2; ++m) {
                f32x4 z = __builtin_amdgcn_mfma_f32_16x16x32_bf16(pa[m][0], vf[dj][0], O[m][dj], 0, 0, 0);
                O[m][dj] = __builtin_amdgcn_mfma_f32_16x16x32_bf16(pa[m][1], vf[dj][1], z, 0, 0, 0);
            }
        __builtin_amdgcn_s_setprio(0);

        if (more) {
            // ---- issue vf(kt+1); latency covered by QK + exp2 below
            vp += 4096;
#pragma unroll
            for (int dj = 0; dj < 4; ++dj)
#pragma unroll
                for (int h = 0; h < 2; ++h)
                    vf[dj][h] = *(const bf16x8*)(vp + (dj * 2 + h) * 512);

            // ---- st(kt+1) = K Q^T (ka latency already covered)
            __builtin_amdgcn_s_setprio(1);
            f32x4 st[2][4];
#pragma unroll
            for (int i = 0; i < 4; ++i)
#pragma unroll
                for (int m = 0; m < 2; ++m) {
                    f32x4 z = __builtin_amdgcn_mfma_f32_16x16x32_bf16(ka[i][0], qt[m][0], zero, 0, 0, 0);
                    st[m][i] = __builtin_amdgcn_mfma_f32_16x16x32_bf16(ka[i][1], qt[m][1], z, 0, 0, 0);
                }
            __builtin_amdgcn_s_setprio(0);
            if (kt + 1 == nkt - 1) {      // diagonal tile (last)
                const int kb = (kt + 1) * 64;
#pragma unroll
                for (int m = 0; m < 2; ++m)
#pragma unroll
                    for (int i = 0; i < 4; ++i)
#pragma unroll
                        for (int r = 0; r < 4; ++r)
                            if (kb + i * 16 + quad * 4 + r > q0 + m * 16 + l15)
                                st[m][i][r] = -INFINITY;
            }
            // ---- p = exp2(s); pack; write P(kt+1) to other buffer
#pragma unroll
            for (int m = 0; m < 2; ++m)
#pragma unroll
                for (int i = 0; i < 4; ++i) {
                    unsigned e0 = __float_as_uint(__builtin_amdgcn_exp2f(st[m][i][0])) + 0x8000u;
                    unsigned e1 = __float_as_uint(__builtin_amdgcn_exp2f(st[m][i][1])) + 0x8000u;
                    unsigned e2 = __float_as_uint(__builtin_amdgcn_exp2f(st[m][i][2])) + 0x8000u;
                    unsigned e3 = __float_as_uint(__builtin_amdgcn_exp2f(st[m][i][3])) + 0x8000u;
                    uint2 pk;
                    pk.x = __builtin_amdgcn_perm(e1, e0, 0x07060302);
                    pk.y = __builtin_amdgcn_perm(e3, e2, 0x07060302);
                    *(uint2*)(bn + pw_off + m * 16 * LDP + i * 16) = pk;
                }
        }
    }

    // ---- epilogue: each wave owns its 32 rows -> O / l -> Y bf16
    const int b = bh / 12, hd = bh % 12;
#pragma unroll
    for (int m = 0; m < 2; ++m)
#pragma unroll
        for (int r = 0; r < 4; ++r) {
            float inv = 1.0f / lac[m][r];
            int t = q0 + 16 * m + quad * 4 + r;
            size_t base = ((size_t)(b * 4096 + t)) * 768 + hd * 64;
#pragma unroll
            for (int dj = 0; dj < 4; ++dj)
                Y[base + dj * 16 + l15] = f2bf(O[m][dj][r] * inv);
        }
}

// ---------------- launch ----------------
extern "C" void kernel_launch(void* const* d_in, const int* in_sizes, int n_in,
                              void* d_out, int out_size, void* d_ws, size_t ws_size,
                              hipStream_t stream) {
    (void)in_sizes; (void)n_in; (void)out_size; (void)ws_size;
    const float* x     = (const float*)d_in[0];
    const float* Wqkv  = (const float*)d_in[1];
    const float* bqkv  = (const float*)d_in[2];
    const float* Wproj = (const float*)d_in[3];
    const float* bproj = (const float*)d_in[4];
    float* out = (float*)d_out;

    char* ws = (char*)d_ws;
    size_t off = 0;
    auto alloc = [&](size_t bytes) -> void* {
        void* p = ws + off;
        off += (bytes + 255) & ~(size_t)255;
        return p;
    };
    unsigned short* xb     = (unsigned short*)alloc((size_t)8192 * 768 * 2);
    unsigned short* WqkvT  = (unsigned short*)alloc((size_t)2304 * 768 * 2);
    unsigned short* WprojT = (unsigned short*)alloc((size_t)768 * 768 * 2);
    unsigned short* QLb    = (unsigned short*)alloc((size_t)24 * 4096 * 64 * 2);
    unsigned short* KLb    = (unsigned short*)alloc((size_t)24 * 4096 * 64 * 2);
    unsigned short* VLb    = (unsigned short*)alloc((size_t)24 * 4096 * 64 * 2);
    unsigned short* Yb     = (unsigned short*)alloc((size_t)8192 * 768 * 2);

    k_convert<<<6144, 256, 0, stream>>>(x, xb, 8192 * 768 / 4);
    dim3 tb(32, 8);
    k_transpose<<<dim3(72, 24), tb, 0, stream>>>(Wqkv, WqkvT, 768, 2304);
    k_transpose<<<dim3(24, 24), tb, 0, stream>>>(Wproj, WprojT, 768, 768);
    k_gemm_qkv<<<dim3(64, 18), 256, 0, stream>>>(xb, WqkvT, bqkv, QLb, KLb, VLb);
    k_attn<<<dim3(1536), 128, 0, stream>>>(QLb, KLb, VLb, Yb);
    k_gemm_proj<<<dim3(64, 6), 256, 0, stream>>>(Yb, WprojT, bproj, out);
}